// Round 6
// baseline (277.300 us; speedup 1.0000x reference)
//
#include <hip/hip_runtime.h>
#include <hip/hip_bf16.h>
#include <stdint.h>

#define D_MODEL 1024
#define SEQ     4096
#define NHEADS  16
#define HEAD_DIM 64
#define NBLK    32      // number of 128-row query blocks per (b,h)
#define MROWS   8192    // B*S
#define NKT     16      // K-tiles (1024/64)

typedef unsigned short u16;
using bf16x8 = __attribute__((ext_vector_type(8))) short;   // 8 bf16 (4 VGPRs)
using f32x4  = __attribute__((ext_vector_type(4))) float;   // MFMA C/D

__device__ __forceinline__ float b2f(u16 b) {
  union { unsigned int u; float f; } v; v.u = ((unsigned int)b) << 16; return v.f;
}
__device__ __forceinline__ u16 f2b(float f) {
  union { float f; unsigned int u; } v; v.f = f;
  return (u16)((v.u + 0x7FFFu + ((v.u >> 16) & 1u)) >> 16);   // RNE, no NaN inputs
}

// async global->LDS, 16B per lane. LDS dest is wave-uniform base (HW adds lane*16).
__device__ __forceinline__ void gload16(const u16* g, u16* l) {
  __builtin_amdgcn_global_load_lds((const __attribute__((address_space(1))) void*)g,
                                   (__attribute__((address_space(3))) void*)l, 16, 0, 0);
}
#define SCHED() __builtin_amdgcn_sched_barrier(0)
#define BAR()   __builtin_amdgcn_s_barrier()

// ---------------------------------------------------------------- prep kernels
__global__ __launch_bounds__(256) void convert_x_kernel(const float* __restrict__ X,
                                                        u16* __restrict__ Xb) {
  size_t idx = (size_t)blockIdx.x * 2048 + (size_t)threadIdx.x * 8;
  float4 a = *(const float4*)(X + idx);
  float4 b = *(const float4*)(X + idx + 4);
  union { u16 u[8]; uint4 v; } o;
  o.u[0]=f2b(a.x); o.u[1]=f2b(a.y); o.u[2]=f2b(a.z); o.u[3]=f2b(a.w);
  o.u[4]=f2b(b.x); o.u[5]=f2b(b.y); o.u[6]=f2b(b.z); o.u[7]=f2b(b.w);
  *(uint4*)(Xb + idx) = o.v;
}

// Wt[z][n][k] = W_z[k][n], bf16
__global__ __launch_bounds__(256) void transpose_w_kernel(const float* __restrict__ Wq,
                                                          const float* __restrict__ Wk,
                                                          const float* __restrict__ Wv,
                                                          const float* __restrict__ Wo,
                                                          u16* __restrict__ Wt) {
  const float* W = (blockIdx.z == 0) ? Wq : (blockIdx.z == 1) ? Wk
                 : (blockIdx.z == 2) ? Wv : Wo;
  u16* out = Wt + (size_t)blockIdx.z * D_MODEL * D_MODEL;
  __shared__ float t[32][33];
  int x = blockIdx.x * 32;          // n base
  int y = blockIdx.y * 32;          // k base
  int tx = threadIdx.x & 31, ty = threadIdx.x >> 5;  // 32 x 8
#pragma unroll
  for (int p = 0; p < 4; ++p)
    t[ty + p * 8][tx] = W[(size_t)(y + ty + p * 8) * D_MODEL + x + tx];
  __syncthreads();
#pragma unroll
  for (int p = 0; p < 4; ++p)
    out[(size_t)(x + ty + p * 8) * D_MODEL + y + tx] = f2b(t[tx][ty + p * 8]);
}

// ---------------------------------------------------------------- GEMM core (8-phase)
// 256x256 tile, 512 thr, 8 waves (2M x 4N), wave tile 128x64, BK=64.
// LDS: 2 dbuf x (A[256][64] + B[256][64]) = 128KB.
// RACE-FREE INVARIANT: all prefetch writes target buf[(t+1)&1] ONLY (the buffer
// whose reads completed before the last barrier of tile t-1). Never the current
// buffer. One vmcnt(0) per K-tile at phase 3, with ~2 phases of slack behind it.
// Chunks XOR-swizzled: LDS(row,c) = G(row, c^(row&7)); reads apply the same XOR.
__device__ __forceinline__ void gemm_core8(const u16* __restrict__ Ag,
                                           const u16* __restrict__ Bg,
                                           int m0, int n0,
                                           u16* smem, f32x4 acc[8][4]) {
  const int tid  = threadIdx.x;
  const int lane = tid & 63;
  const int w    = tid >> 6;             // 0..7
  const int wm   = w >> 2, wn = w & 3;
  const int fr   = lane & 15, fg = lane >> 4;

#pragma unroll
  for (int mf = 0; mf < 8; ++mf)
#pragma unroll
    for (int nf = 0; nf < 4; ++nf)
      acc[mf][nf] = (f32x4)(0.0f);

  // staging: wave w covers rows [w*16, w*16+16) of each 128-row half
  const int srow = lane >> 3;            // 0..7
  const int schk = (lane & 7) ^ srow;    // pre-swizzled source chunk
  const u16* agp = Ag + (size_t)(m0 + w * 16 + srow) * D_MODEL + schk * 8;
  const u16* bgp = Bg + (size_t)(n0 + w * 16 + srow) * D_MODEL + schk * 8;

  // fragment read bases (row&7 == fr&7 for all frags)
  const int arow = (wm * 128 + fr) * 64;            // + mf*1024 + chunk
  const int brow = 16384 + (wn * 64 + fr) * 64;     // + nf*1024 + chunk
  const int c0 = (fg ^ (fr & 7)) * 8;               // kk=0 chunk (u16 units)
  const int c1 = ((4 + fg) ^ (fr & 7)) * 8;         // kk=1

  auto stA = [&](int kt, int h) {
    u16* dst = smem + (kt & 1) * 32768 + h * 8192 + w * 1024;
    const u16* src = agp + (size_t)(h * 128) * D_MODEL + (size_t)kt * 64;
    gload16(src, dst);
    gload16(src + (size_t)8 * D_MODEL, dst + 512);
  };
  auto stB = [&](int kt, int h) {
    u16* dst = smem + (kt & 1) * 32768 + 16384 + h * 8192 + w * 1024;
    const u16* src = bgp + (size_t)(h * 128) * D_MODEL + (size_t)kt * 64;
    gload16(src, dst);
    gload16(src + (size_t)8 * D_MODEL, dst + 512);
  };

  // prologue: stage all of tile 0 into buf0
  stA(0, 0); stB(0, 0); stA(0, 1); stB(0, 1);
  asm volatile("s_waitcnt vmcnt(0)" ::: "memory");
  SCHED(); BAR(); SCHED();

  bf16x8 a[4], bk0[4], bk1[4];
  for (int t = 0; t < NKT; ++t) {
    const int bo = (t & 1) * 32768;
    // ---- phase 0: mf0-3, kk0 (8 ds_reads) ; stage t+1: A0,B0 -> other buffer ----
#pragma unroll
    for (int i = 0; i < 4; ++i) a[i]   = *(const bf16x8*)(smem + bo + arow + i * 1024 + c0);
#pragma unroll
    for (int i = 0; i < 4; ++i) bk0[i] = *(const bf16x8*)(smem + bo + brow + i * 1024 + c0);
    if (t + 1 < NKT) { stA(t + 1, 0); stB(t + 1, 0); }
    SCHED(); BAR();
    asm volatile("s_waitcnt lgkmcnt(0)" ::: "memory");
    SCHED();
    __builtin_amdgcn_s_setprio(1);
#pragma unroll
    for (int i = 0; i < 4; ++i)
#pragma unroll
      for (int nf = 0; nf < 4; ++nf)
        acc[i][nf] = __builtin_amdgcn_mfma_f32_16x16x32_bf16(a[i], bk0[nf], acc[i][nf], 0, 0, 0);
    __builtin_amdgcn_s_setprio(0);
    SCHED(); BAR(); SCHED();
    // ---- phase 1: mf0-3, kk1 (8 ds_reads) ; stage t+1: A1,B1 -> other buffer ----
#pragma unroll
    for (int i = 0; i < 4; ++i) a[i]   = *(const bf16x8*)(smem + bo + arow + i * 1024 + c1);
#pragma unroll
    for (int i = 0; i < 4; ++i) bk1[i] = *(const bf16x8*)(smem + bo + brow + i * 1024 + c1);
    if (t + 1 < NKT) { stA(t + 1, 1); stB(t + 1, 1); }
    SCHED(); BAR();
    asm volatile("s_waitcnt lgkmcnt(0)" ::: "memory");
    SCHED();
    __builtin_amdgcn_s_setprio(1);
#pragma unroll
    for (int i = 0; i < 4; ++i)
#pragma unroll
      for (int nf = 0; nf < 4; ++nf)
        acc[i][nf] = __builtin_amdgcn_mfma_f32_16x16x32_bf16(a[i], bk1[nf], acc[i][nf], 0, 0, 0);
    __builtin_amdgcn_s_setprio(0);
    SCHED(); BAR(); SCHED();
    // ---- phase 2: mf4-7, kk0 (4 ds_reads; bk0 reused) ----
#pragma unroll
    for (int i = 0; i < 4; ++i) a[i] = *(const bf16x8*)(smem + bo + arow + (4 + i) * 1024 + c0);
    SCHED(); BAR();
    asm volatile("s_waitcnt lgkmcnt(0)" ::: "memory");
    SCHED();
    __builtin_amdgcn_s_setprio(1);
#pragma unroll
    for (int i = 0; i < 4; ++i)
#pragma unroll
      for (int nf = 0; nf < 4; ++nf)
        acc[4 + i][nf] = __builtin_amdgcn_mfma_f32_16x16x32_bf16(a[i], bk0[nf], acc[4 + i][nf], 0, 0, 0);
    __builtin_amdgcn_s_setprio(0);
    SCHED(); BAR(); SCHED();
    // ---- phase 3: mf4-7, kk1 (4 ds_reads; bk1 reused) + slack-drained vmcnt ----
#pragma unroll
    for (int i = 0; i < 4; ++i) a[i] = *(const bf16x8*)(smem + bo + arow + (4 + i) * 1024 + c1);
    asm volatile("s_waitcnt vmcnt(0)" ::: "memory");   // t+1 loads: issued >=2 phases ago
    SCHED(); BAR();
    asm volatile("s_waitcnt lgkmcnt(0)" ::: "memory");
    SCHED();
    __builtin_amdgcn_s_setprio(1);
#pragma unroll
    for (int i = 0; i < 4; ++i)
#pragma unroll
      for (int nf = 0; nf < 4; ++nf)
        acc[4 + i][nf] = __builtin_amdgcn_mfma_f32_16x16x32_bf16(a[i], bk1[nf], acc[4 + i][nf], 0, 0, 0);
    __builtin_amdgcn_s_setprio(0);
    SCHED(); BAR(); SCHED();
  }
}

// QKV projection. grid = 384 linear (32 m x 4 n x 3 z); XCD-chunked bijective swizzle.
__global__ __launch_bounds__(512, 2) void qkv_gemm_kernel(const u16* __restrict__ Xb,
                                                          const u16* __restrict__ Wt,
                                                          const float* __restrict__ bq,
                                                          const float* __restrict__ bk,
                                                          const float* __restrict__ bv,
                                                          u16* __restrict__ Qb,
                                                          u16* __restrict__ Kb,
                                                          u16* __restrict__ Vt) {
  __shared__ u16 smem[65536];   // 128KB: staging dbufs in [0,32768); epilogue C[256][256]
  const int id  = blockIdx.x;
  const int lin = (id & 7) * 48 + (id >> 3);    // bijective (384 = 8*48), m-contig per XCD
  const int mt  = lin / 12;
  const int rem = lin % 12;
  const int nt  = rem / 3;
  const int which = rem % 3;
  const int m0 = mt * 256, n0 = nt * 256;
  const u16* Bg = Wt + (size_t)which * D_MODEL * D_MODEL;
  f32x4 acc[8][4];
  gemm_core8(Xb, Bg, m0, n0, smem, acc);

  const float* bias = (which == 0) ? bq : (which == 1) ? bk : bv;
  const float scale = (which == 0) ? 0.125f : 1.0f;
  const int lane = threadIdx.x & 63, w = threadIdx.x >> 6;
  const int wm = w >> 2, wn = w & 3;
  const int fr = lane & 15, fg = lane >> 4;

  // C -> LDS (scalar; transposed for V so global stores coalesce along s)
  if (which < 2) {
#pragma unroll
    for (int nf = 0; nf < 4; ++nf) {
      const int n = wn * 64 + nf * 16 + fr;
      const float bn = bias[n0 + n];
#pragma unroll
      for (int mf = 0; mf < 8; ++mf)
#pragma unroll
        for (int r = 0; r < 4; ++r) {
          const int row = wm * 128 + mf * 16 + fg * 4 + r;
          smem[row * 256 + n] = f2b((acc[mf][nf][r] + bn) * scale);
        }
    }
  } else {
#pragma unroll
    for (int nf = 0; nf < 4; ++nf) {
      const int n = wn * 64 + nf * 16 + fr;
      const float bn = bias[n0 + n];
#pragma unroll
      for (int mf = 0; mf < 8; ++mf)
#pragma unroll
        for (int r = 0; r < 4; ++r) {
          const int row = wm * 128 + mf * 16 + fg * 4 + r;
          smem[n * 256 + row] = f2b(acc[mf][nf][r] + bn);
        }
    }
  }
  __syncthreads();

  // wide coalesced stores: 2048 chunks of 64B, 4 per thread
  u16* outQK = (which == 0) ? Qb : Kb;
#pragma unroll
  for (int it = 0; it < 4; ++it) {
    const int c   = it * 512 + threadIdx.x;
    const int row = c >> 3;
    const int o32 = (c & 7) * 32;
    const u16* src = smem + row * 256 + o32;
    uint4 v0 = *(const uint4*)(src);
    uint4 v1 = *(const uint4*)(src + 8);
    uint4 v2 = *(const uint4*)(src + 16);
    uint4 v3 = *(const uint4*)(src + 24);
    u16* dst;
    if (which < 2) {
      const int mg = m0 + row;
      const int bb = mg >> 12, s = mg & 4095;
      const int nn = n0 + o32;
      const int h  = nn >> 6, d0 = nn & 63;
      dst = outQK + ((size_t)(bb * NHEADS + h) * SEQ + s) * HEAD_DIM + d0;
    } else {
      const int nn = n0 + row;
      const int h  = nn >> 6, d = nn & 63;
      const int bb = m0 >> 12;
      dst = Vt + ((size_t)(bb * NHEADS + h) * HEAD_DIM + d) * SEQ + (m0 & 4095) + o32;
    }
    *(uint4*)dst = v0; *(uint4*)(dst + 8) = v1;
    *(uint4*)(dst + 16) = v2; *(uint4*)(dst + 24) = v3;
  }
}

// O projection: grid = 128 linear (32 m x 4 n). Y = X2 @ Wo + bo (bf16 out)
__global__ __launch_bounds__(512, 2) void o_gemm_kernel(const u16* __restrict__ X2,
                                                        const u16* __restrict__ WtO,
                                                        const float* __restrict__ bo,
                                                        u16* __restrict__ Y) {
  __shared__ u16 smem[65536];
  const int id  = blockIdx.x;
  const int lin = (id & 7) * 16 + (id >> 3);    // bijective (128 = 8*16)
  const int m0  = (lin >> 2) * 256;
  const int n0  = (lin & 3) * 256;
  f32x4 acc[8][4];
  gemm_core8(X2, WtO, m0, n0, smem, acc);

  const int lane = threadIdx.x & 63, w = threadIdx.x >> 6;
  const int wm = w >> 2, wn = w & 3;
  const int fr = lane & 15, fg = lane >> 4;
#pragma unroll
  for (int nf = 0; nf < 4; ++nf) {
    const int n = wn * 64 + nf * 16 + fr;
    const float bn = bo[n0 + n];
#pragma unroll
    for (int mf = 0; mf < 8; ++mf)
#pragma unroll
      for (int r = 0; r < 4; ++r) {
        const int row = wm * 128 + mf * 16 + fg * 4 + r;
        smem[row * 256 + n] = f2b(acc[mf][nf][r] + bn);
      }
  }
  __syncthreads();
#pragma unroll
  for (int it = 0; it < 4; ++it) {
    const int c   = it * 512 + threadIdx.x;
    const int row = c >> 3;
    const int o32 = (c & 7) * 32;
    const u16* src = smem + row * 256 + o32;
    uint4 v0 = *(const uint4*)(src);
    uint4 v1 = *(const uint4*)(src + 8);
    uint4 v2 = *(const uint4*)(src + 16);
    uint4 v3 = *(const uint4*)(src + 24);
    u16* dst = Y + (size_t)(m0 + row) * D_MODEL + n0 + o32;
    *(uint4*)dst = v0; *(uint4*)(dst + 8) = v1;
    *(uint4*)(dst + 16) = v2; *(uint4*)(dst + 24) = v3;
  }
}

// ---------------------------------------------------------------- attention
// One block per (b,h,qblock). 4 waves, each owns 32 query rows.
#define PSTR 264   // P lds row stride (elements)
#define OSTR 72    // O staging stride within Ps for coalesced store

template <int NF>   // number of 16-key fragments in window (16 normal, 8 last block)
__device__ __forceinline__ void attn_body(const u16* __restrict__ Qp,
                                          const u16* __restrict__ Kp,
                                          const u16* __restrict__ Vp,
                                          u16* __restrict__ X2p,
                                          u16* Ps, float* rs) {
  const int lane = threadIdx.x & 63;
  const int fr = lane & 15, fg = lane >> 4;

  bf16x8 qf[2][2];
#pragma unroll
  for (int mf = 0; mf < 2; ++mf)
#pragma unroll
    for (int kk = 0; kk < 2; ++kk)
      qf[mf][kk] = *(const bf16x8*)(Qp + (mf * 16 + fr) * HEAD_DIM + kk * 32 + fg * 8);

  f32x4 sacc[2][NF];
#pragma unroll
  for (int mf = 0; mf < 2; ++mf)
#pragma unroll
    for (int nf = 0; nf < NF; ++nf) sacc[mf][nf] = (f32x4)(0.0f);

#pragma unroll
  for (int nf = 0; nf < NF; ++nf) {
    bf16x8 kf0 = *(const bf16x8*)(Kp + (nf * 16 + fr) * HEAD_DIM + fg * 8);
    bf16x8 kf1 = *(const bf16x8*)(Kp + (nf * 16 + fr) * HEAD_DIM + 32 + fg * 8);
#pragma unroll
    for (int mf = 0; mf < 2; ++mf) {
      sacc[mf][nf] = __builtin_amdgcn_mfma_f32_16x16x32_bf16(qf[mf][0], kf0, sacc[mf][nf], 0, 0, 0);
      sacc[mf][nf] = __builtin_amdgcn_mfma_f32_16x16x32_bf16(qf[mf][1], kf1, sacc[mf][nf], 0, 0, 0);
    }
  }

  // softmax: row m = mf*16 + fg*4 + r lives in lanes sharing fg, cols nf*16+fr
#pragma unroll
  for (int mf = 0; mf < 2; ++mf) {
#pragma unroll
    for (int r = 0; r < 4; ++r) {
      float mx = -1e30f;
#pragma unroll
      for (int nf = 0; nf < NF; ++nf) mx = fmaxf(mx, sacc[mf][nf][r]);
      mx = fmaxf(mx, __shfl_xor(mx, 1));
      mx = fmaxf(mx, __shfl_xor(mx, 2));
      mx = fmaxf(mx, __shfl_xor(mx, 4));
      mx = fmaxf(mx, __shfl_xor(mx, 8));
      float sm = 0.f;
#pragma unroll
      for (int nf = 0; nf < NF; ++nf) {
        float p = __expf(sacc[mf][nf][r] - mx);
        sacc[mf][nf][r] = p;
        sm += p;
      }
      sm += __shfl_xor(sm, 1);
      sm += __shfl_xor(sm, 2);
      sm += __shfl_xor(sm, 4);
      sm += __shfl_xor(sm, 8);
      if (fr == 0) rs[mf * 16 + fg * 4 + r] = sm;
    }
  }

  // P (exp, unnormalized) -> LDS bf16
#pragma unroll
  for (int mf = 0; mf < 2; ++mf)
#pragma unroll
    for (int nf = 0; nf < NF; ++nf)
#pragma unroll
      for (int r = 0; r < 4; ++r)
        Ps[(mf * 16 + fg * 4 + r) * PSTR + nf * 16 + fr] = f2b(sacc[mf][nf][r]);
  __syncthreads();

  // OUT^T[d][q] = sum_kk V^T[d][kk] * P^T[kk][q]
  f32x4 oacc[4][2];
#pragma unroll
  for (int mf2 = 0; mf2 < 4; ++mf2)
#pragma unroll
    for (int nf2 = 0; nf2 < 2; ++nf2) oacc[mf2][nf2] = (f32x4)(0.0f);

#pragma unroll
  for (int ks = 0; ks < NF / 2; ++ks) {
    bf16x8 vf[4];
#pragma unroll
    for (int mf2 = 0; mf2 < 4; ++mf2)
      vf[mf2] = *(const bf16x8*)(Vp + (size_t)(mf2 * 16 + fr) * SEQ + ks * 32 + fg * 8);
#pragma unroll
    for (int nf2 = 0; nf2 < 2; ++nf2) {
      bf16x8 pf = *(const bf16x8*)(Ps + (nf2 * 16 + fr) * PSTR + ks * 32 + fg * 8);
#pragma unroll
      for (int mf2 = 0; mf2 < 4; ++mf2)
        oacc[mf2][nf2] = __builtin_amdgcn_mfma_f32_16x16x32_bf16(vf[mf2], pf,
                                                                 oacc[mf2][nf2], 0, 0, 0);
    }
  }
  __syncthreads();   // done reading P; reuse Ps for O staging

  // O -> LDS (normalized, [32 q][64 d] at stride OSTR), then 64B coalesced stores
#pragma unroll
  for (int nf2 = 0; nf2 < 2; ++nf2) {
    const int q = nf2 * 16 + fr;
    const float inv = 1.0f / rs[q];
#pragma unroll
    for (int mf2 = 0; mf2 < 4; ++mf2)
#pragma unroll
      for (int r = 0; r < 4; ++r)
        Ps[q * OSTR + mf2 * 16 + fg * 4 + r] = f2b(oacc[mf2][nf2][r] * inv);
  }
  __syncthreads();
  const int q2 = lane >> 1, hf = (lane & 1) * 32;
  const u16* osrc = Ps + q2 * OSTR + hf;
  uint4 o0 = *(const uint4*)(osrc);
  uint4 o1 = *(const uint4*)(osrc + 8);
  uint4 o2 = *(const uint4*)(osrc + 16);
  uint4 o3 = *(const uint4*)(osrc + 24);
  u16* dst = X2p + (size_t)q2 * D_MODEL + hf;
  *(uint4*)dst = o0; *(uint4*)(dst + 8) = o1;
  *(uint4*)(dst + 16) = o2; *(uint4*)(dst + 24) = o3;
}

__global__ __launch_bounds__(256, 2) void attn_kernel(const u16* __restrict__ Qb,
                                                      const u16* __restrict__ Kb,
                                                      const u16* __restrict__ Vt,
                                                      u16* __restrict__ X2) {
  __shared__ u16 Ps[4][32 * PSTR];
  __shared__ float rs[4][32];
  const int bx = blockIdx.x;
  const int bh = bx >> 5, i = bx & 31;
  const int w = threadIdx.x >> 6;
  const int b = bh >> 4, h = bh & 15;
  const u16* Qp = Qb + ((size_t)bh * SEQ + i * 128 + w * 32) * HEAD_DIM;
  const u16* Kp = Kb + ((size_t)bh * SEQ + i * 128) * HEAD_DIM;
  const u16* Vp = Vt + (size_t)bh * HEAD_DIM * SEQ + i * 128;
  u16* X2p = X2 + ((size_t)(b * SEQ) + i * 128 + w * 32) * D_MODEL + h * HEAD_DIM;
  if (i == NBLK - 1) attn_body<8>(Qp, Kp, Vp, X2p, Ps[w], rs[w]);
  else               attn_body<16>(Qp, Kp, Vp, X2p, Ps[w], rs[w]);
}

// ---------------------------------------------------------------- layernorm
__global__ __launch_bounds__(256) void ln_kernel(const float* __restrict__ hidden,
                                                 const u16* __restrict__ Y,
                                                 const float* __restrict__ lw,
                                                 const float* __restrict__ lb,
                                                 float* __restrict__ out) {
  const int row = blockIdx.x;
  const int tid = threadIdx.x;
  const size_t base = (size_t)row * D_MODEL + tid * 4;
  float4 h = *(const float4*)(hidden + base);
  union { uint2 v; u16 u[4]; } y;
  y.v = *(const uint2*)(Y + base);
  float x0 = h.x + b2f(y.u[0]);
  float x1 = h.y + b2f(y.u[1]);
  float x2 = h.z + b2f(y.u[2]);
  float x3 = h.w + b2f(y.u[3]);
  float sum = x0 + x1 + x2 + x3;
  float sq  = x0 * x0 + x1 * x1 + x2 * x2 + x3 * x3;
#pragma unroll
  for (int off = 32; off >= 1; off >>= 1) {
    sum += __shfl_down(sum, off);
    sq  += __shfl_down(sq, off);
  }
  __shared__ float s1[4], s2[4];
  const int w = tid >> 6, lane = tid & 63;
  if (lane == 0) { s1[w] = sum; s2[w] = sq; }
  __syncthreads();
  const float ts = s1[0] + s1[1] + s1[2] + s1[3];
  const float tq = s2[0] + s2[1] + s2[2] + s2[3];
  const float mu = ts * (1.0f / 1024.0f);
  const float var = tq * (1.0f / 1024.0f) - mu * mu;
  const float rstd = rsqrtf(var + 1e-5f);
  float4 lwv = *(const float4*)(lw + tid * 4);
  float4 lbv = *(const float4*)(lb + tid * 4);
  float4 o;
  o.x = (x0 - mu) * rstd * lwv.x + lbv.x;
  o.y = (x1 - mu) * rstd * lwv.y + lbv.y;
  o.z = (x2 - mu) * rstd * lwv.z + lbv.z;
  o.w = (x3 - mu) * rstd * lwv.w + lbv.w;
  *(float4*)(out + base) = o;
}

// ---------------------------------------------------------------- launcher
extern "C" void kernel_launch(void* const* d_in, const int* in_sizes, int n_in,
                              void* d_out, int out_size, void* d_ws, size_t ws_size,
                              hipStream_t stream) {
  const float* hidden = (const float*)d_in[0];
  const float* Wq = (const float*)d_in[1];
  const float* bq = (const float*)d_in[2];
  const float* Wk = (const float*)d_in[3];
  const float* bk = (const float*)d_in[4];
  const float* Wv = (const float*)d_in[5];
  const float* bv = (const float*)d_in[6];
  const float* Wo = (const float*)d_in[7];
  const float* bo = (const float*)d_in[8];
  const float* lw = (const float*)d_in[9];
  const float* lb = (const float*)d_in[10];
  float* out = (float*)d_out;

  u16* Xb = (u16*)d_ws;                                  // [8192][1024]
  u16* Wt = Xb + (size_t)MROWS * D_MODEL;                // [4][1024 n][1024 k]
  u16* Qb = Wt + (size_t)4 * D_MODEL * D_MODEL;          // [32][4096][64] (q*0.125)
  u16* Kb = Qb + (size_t)32 * SEQ * HEAD_DIM;            // [32][4096][64]
  u16* Vt = Kb + (size_t)32 * SEQ * HEAD_DIM;            // [32][64][4096]
  u16* X2 = Vt + (size_t)32 * SEQ * HEAD_DIM;            // [8192][1024] attn out
  u16* Y  = X2 + (size_t)MROWS * D_MODEL;                // [8192][1024] o-proj out

  convert_x_kernel<<<4096, 256, 0, stream>>>(hidden, Xb);
  transpose_w_kernel<<<dim3(32, 32, 4), 256, 0, stream>>>(Wq, Wk, Wv, Wo, Wt);
  qkv_gemm_kernel<<<384, 512, 0, stream>>>(Xb, Wt, bq, bk, bv, Qb, Kb, Vt);
  attn_kernel<<<1024, 256, 0, stream>>>(Qb, Kb, Vt, X2);
  o_gemm_kernel<<<128, 512, 0, stream>>>(X2, Wt + (size_t)3 * D_MODEL * D_MODEL, bo, Y);
  ln_kernel<<<MROWS, 256, 0, stream>>>(hidden, Y, lw, lb, out);
}

// Round 7
// 255.442 us; speedup vs baseline: 1.0856x; 1.0856x over previous
//
#include <hip/hip_runtime.h>
#include <hip/hip_bf16.h>
#include <stdint.h>

#define D_MODEL 1024
#define SEQ     4096
#define NHEADS  16
#define HEAD_DIM 64
#define NBLK    32      // number of 128-row query blocks per (b,h)
#define MROWS   8192    // B*S
#define NKT     16      // K-tiles (1024/64)

typedef unsigned short u16;
using bf16x8 = __attribute__((ext_vector_type(8))) short;   // 8 bf16 (4 VGPRs)
using f32x4  = __attribute__((ext_vector_type(4))) float;   // MFMA C/D

__device__ __forceinline__ float b2f(u16 b) {
  union { unsigned int u; float f; } v; v.u = ((unsigned int)b) << 16; return v.f;
}
__device__ __forceinline__ u16 f2b(float f) {
  union { float f; unsigned int u; } v; v.f = f;
  return (u16)((v.u + 0x7FFFu + ((v.u >> 16) & 1u)) >> 16);   // RNE, no NaN inputs
}

// async global->LDS, 16B per lane. LDS dest is wave-uniform base (HW adds lane*16).
__device__ __forceinline__ void gload16(const u16* g, u16* l) {
  __builtin_amdgcn_global_load_lds((const __attribute__((address_space(1))) void*)g,
                                   (__attribute__((address_space(3))) void*)l, 16, 0, 0);
}
#define SCHED() __builtin_amdgcn_sched_barrier(0)
#define BAR()   __builtin_amdgcn_s_barrier()
// per-wave LDS ordering (no block barrier): wave's own writes/reads complete
#define WSYNC() do { asm volatile("s_waitcnt lgkmcnt(0)" ::: "memory"); \
                     __builtin_amdgcn_sched_barrier(0); } while (0)

// ---------------------------------------------------------------- prep kernels
__global__ __launch_bounds__(256) void convert_x_kernel(const float* __restrict__ X,
                                                        u16* __restrict__ Xb) {
  size_t idx = (size_t)blockIdx.x * 2048 + (size_t)threadIdx.x * 8;
  float4 a = *(const float4*)(X + idx);
  float4 b = *(const float4*)(X + idx + 4);
  union { u16 u[8]; uint4 v; } o;
  o.u[0]=f2b(a.x); o.u[1]=f2b(a.y); o.u[2]=f2b(a.z); o.u[3]=f2b(a.w);
  o.u[4]=f2b(b.x); o.u[5]=f2b(b.y); o.u[6]=f2b(b.z); o.u[7]=f2b(b.w);
  *(uint4*)(Xb + idx) = o.v;
}

// Wt[z][n][k] = W_z[k][n], bf16
__global__ __launch_bounds__(256) void transpose_w_kernel(const float* __restrict__ Wq,
                                                          const float* __restrict__ Wk,
                                                          const float* __restrict__ Wv,
                                                          const float* __restrict__ Wo,
                                                          u16* __restrict__ Wt) {
  const float* W = (blockIdx.z == 0) ? Wq : (blockIdx.z == 1) ? Wk
                 : (blockIdx.z == 2) ? Wv : Wo;
  u16* out = Wt + (size_t)blockIdx.z * D_MODEL * D_MODEL;
  __shared__ float t[32][33];
  int x = blockIdx.x * 32;          // n base
  int y = blockIdx.y * 32;          // k base
  int tx = threadIdx.x & 31, ty = threadIdx.x >> 5;  // 32 x 8
#pragma unroll
  for (int p = 0; p < 4; ++p)
    t[ty + p * 8][tx] = W[(size_t)(y + ty + p * 8) * D_MODEL + x + tx];
  __syncthreads();
#pragma unroll
  for (int p = 0; p < 4; ++p)
    out[(size_t)(x + ty + p * 8) * D_MODEL + y + tx] = f2b(t[tx][ty + p * 8]);
}

// ---------------------------------------------------------------- GEMM core
// (round-4 structure, best known here) 128x128 tile, 4 waves (2x2), wave tile
// 64x64, BK=64. Double-buffered pipelined loop: STAGE(t+1) issued before
// compute(t); counted s_waitcnt vmcnt(8) + raw s_barrier (no full drain).
// Chunks XOR-swizzled: LDS(row,c) = G(row, c^(row&7)); reads apply same XOR.
__device__ __forceinline__ void gemm_core(const u16* __restrict__ Ag,
                                          const u16* __restrict__ Bg,
                                          int m0, int n0,
                                          u16* smem, f32x4 acc[4][4]) {
  const int tid  = threadIdx.x;
  const int lane = tid & 63;
  const int w    = tid >> 6;
  const int wm   = w >> 1, wn = w & 1;
  const int fr   = lane & 15;
  const int fg   = lane >> 4;

#pragma unroll
  for (int mf = 0; mf < 4; ++mf)
#pragma unroll
    for (int nf = 0; nf < 4; ++nf)
      acc[mf][nf] = (f32x4)(0.0f);

  // staging: wave w owns rows [w*32, w*32+32), 4 chunks of 8 rows
  const int srow   = lane >> 3;                  // 0..7
  const int schunk = (lane & 7) ^ srow;          // pre-swizzled source chunk
  const u16* agp = Ag + (size_t)(m0 + w * 32 + srow) * D_MODEL + schunk * 8;
  const u16* bgp = Bg + (size_t)(n0 + w * 32 + srow) * D_MODEL + schunk * 8;

  // fragment read bases; swizzled chunk offsets (row&7 == fr&7 for all mf)
  const int c0 = fg ^ (fr & 7);                  // kk=0 chunk
  const int c1 = (4 + fg) ^ (fr & 7);            // kk=1 chunk
  const u16* ars = smem + (wm * 64 + fr) * 64;
  const u16* brs = smem + 8192 + (wn * 64 + fr) * 64;

  auto stage = [&](int kt, int buf) {
    u16* a_ = smem + buf * 16384 + w * 2048;
    u16* b_ = smem + buf * 16384 + 8192 + w * 2048;
#pragma unroll
    for (int j = 0; j < 4; ++j) {
      gload16(agp + (size_t)kt * 64 + (size_t)(j * 8) * D_MODEL, a_ + j * 512);
      gload16(bgp + (size_t)kt * 64 + (size_t)(j * 8) * D_MODEL, b_ + j * 512);
    }
  };

  stage(0, 0);
  for (int kt = 0; kt < NKT; ++kt) {
    if (kt + 1 < NKT) {
      stage(kt + 1, (kt + 1) & 1);
      asm volatile("s_waitcnt vmcnt(8)" ::: "memory");   // tile kt's 8 loads done
    } else {
      asm volatile("s_waitcnt vmcnt(0)" ::: "memory");
    }
    SCHED(); BAR(); SCHED();
    const int boff = (kt & 1) * 16384;
    bf16x8 a0[4], a1[4], b0[4], b1[4];
#pragma unroll
    for (int mf = 0; mf < 4; ++mf) {
      a0[mf] = *(const bf16x8*)(ars + boff + mf * 1024 + c0 * 8);
      a1[mf] = *(const bf16x8*)(ars + boff + mf * 1024 + c1 * 8);
    }
#pragma unroll
    for (int nf = 0; nf < 4; ++nf) {
      b0[nf] = *(const bf16x8*)(brs + boff + nf * 1024 + c0 * 8);
      b1[nf] = *(const bf16x8*)(brs + boff + nf * 1024 + c1 * 8);
    }
#pragma unroll
    for (int mf = 0; mf < 4; ++mf)
#pragma unroll
      for (int nf = 0; nf < 4; ++nf)
        acc[mf][nf] = __builtin_amdgcn_mfma_f32_16x16x32_bf16(a0[mf], b0[nf],
                                                              acc[mf][nf], 0, 0, 0);
#pragma unroll
    for (int mf = 0; mf < 4; ++mf)
#pragma unroll
      for (int nf = 0; nf < 4; ++nf)
        acc[mf][nf] = __builtin_amdgcn_mfma_f32_16x16x32_bf16(a1[mf], b1[nf],
                                                              acc[mf][nf], 0, 0, 0);
    SCHED(); BAR(); SCHED();
  }
}

// QKV projection. grid = 1536 linear; bijective chunked XCD swizzle, z innermost
__global__ __launch_bounds__(256, 2) void qkv_gemm_kernel(const u16* __restrict__ Xb,
                                                          const u16* __restrict__ Wt,
                                                          const float* __restrict__ bq,
                                                          const float* __restrict__ bk,
                                                          const float* __restrict__ bv,
                                                          u16* __restrict__ Qb,
                                                          u16* __restrict__ Kb,
                                                          u16* __restrict__ Vt) {
  __shared__ u16 smem[32768];   // 64KB: 2 staging buffers; epilogue reuses [0,16384)
  const int id  = blockIdx.x;
  const int lin = (id & 7) * 192 + (id >> 3);   // XCD-chunked, bijective (1536 = 8*192)
  const int which = lin % 3;
  const int nr  = lin / 3;
  const int n0  = (nr & 7) * 128;
  const int m0  = (nr >> 3) * 128;
  const u16* Bg = Wt + (size_t)which * D_MODEL * D_MODEL;
  f32x4 acc[4][4];
  gemm_core(Xb, Bg, m0, n0, smem, acc);

  const float* bias = (which == 0) ? bq : (which == 1) ? bk : bv;
  const float scale = (which == 0) ? 0.125f : 1.0f;
  const int lane = threadIdx.x & 63, w = threadIdx.x >> 6;
  const int wm = w >> 1, wn = w & 1;
  const int fr = lane & 15, fg = lane >> 4;
  const int mb = wm * 64 + fg * 4;
  const int nb = wn * 64 + fr;

  // C -> LDS (scalar; transposed for V so global stores coalesce along s)
  if (which < 2) {
#pragma unroll
    for (int nf = 0; nf < 4; ++nf) {
      const int n = nb + nf * 16;
      const float bn = bias[n0 + n];
#pragma unroll
      for (int mf = 0; mf < 4; ++mf)
#pragma unroll
        for (int r = 0; r < 4; ++r)
          smem[(mb + mf * 16 + r) * 128 + n] = f2b((acc[mf][nf][r] + bn) * scale);
    }
  } else {
#pragma unroll
    for (int nf = 0; nf < 4; ++nf) {
      const int n = nb + nf * 16;
      const float bn = bias[n0 + n];
#pragma unroll
      for (int mf = 0; mf < 4; ++mf)
#pragma unroll
        for (int r = 0; r < 4; ++r)
          smem[n * 128 + mb + mf * 16 + r] = f2b(acc[mf][nf][r] + bn);
    }
  }
  __syncthreads();

  // wide coalesced stores: 512 chunks of 64B, 2 per thread
  u16* outQK = (which == 0) ? Qb : Kb;
#pragma unroll
  for (int it = 0; it < 2; ++it) {
    const int c   = threadIdx.x + it * 256;
    const int row = c >> 2;
    const int o32 = (c & 3) * 32;
    const u16* src = smem + row * 128 + o32;
    uint4 v0 = *(const uint4*)(src);
    uint4 v1 = *(const uint4*)(src + 8);
    uint4 v2 = *(const uint4*)(src + 16);
    uint4 v3 = *(const uint4*)(src + 24);
    u16* dst;
    if (which < 2) {
      const int mg = m0 + row;
      const int bb = mg >> 12, s = mg & 4095;
      const int n  = n0 + o32;
      const int h  = n >> 6, d0 = n & 63;
      dst = outQK + ((size_t)(bb * NHEADS + h) * SEQ + s) * HEAD_DIM + d0;
    } else {
      const int n  = n0 + row;
      const int h  = n >> 6, d = n & 63;
      const int bb = m0 >> 12;
      dst = Vt + ((size_t)(bb * NHEADS + h) * HEAD_DIM + d) * SEQ + (m0 & 4095) + o32;
    }
    *(uint4*)dst = v0; *(uint4*)(dst + 8) = v1;
    *(uint4*)(dst + 16) = v2; *(uint4*)(dst + 24) = v3;
  }
}

// O projection: grid = 512 linear, same swizzle family. Y = X2 @ Wo + bo (bf16 out)
__global__ __launch_bounds__(256, 2) void o_gemm_kernel(const u16* __restrict__ X2,
                                                        const u16* __restrict__ WtO,
                                                        const float* __restrict__ bo,
                                                        u16* __restrict__ Y) {
  __shared__ u16 smem[32768];
  const int id  = blockIdx.x;
  const int lin = (id & 7) * 64 + (id >> 3);    // bijective (512 = 8*64)
  const int n0  = (lin & 7) * 128;
  const int m0  = (lin >> 3) * 128;
  f32x4 acc[4][4];
  gemm_core(X2, WtO, m0, n0, smem, acc);

  const int lane = threadIdx.x & 63, w = threadIdx.x >> 6;
  const int wm = w >> 1, wn = w & 1;
  const int fr = lane & 15, fg = lane >> 4;
  const int mb = wm * 64 + fg * 4;
  const int nb = wn * 64 + fr;
#pragma unroll
  for (int nf = 0; nf < 4; ++nf) {
    const int n = nb + nf * 16;
    const float bn = bo[n0 + n];
#pragma unroll
    for (int mf = 0; mf < 4; ++mf)
#pragma unroll
      for (int r = 0; r < 4; ++r)
        smem[(mb + mf * 16 + r) * 128 + n] = f2b(acc[mf][nf][r] + bn);
  }
  __syncthreads();
#pragma unroll
  for (int it = 0; it < 2; ++it) {
    const int c   = threadIdx.x + it * 256;
    const int row = c >> 2;
    const int o32 = (c & 3) * 32;
    const u16* src = smem + row * 128 + o32;
    uint4 v0 = *(const uint4*)(src);
    uint4 v1 = *(const uint4*)(src + 8);
    uint4 v2 = *(const uint4*)(src + 16);
    uint4 v3 = *(const uint4*)(src + 24);
    u16* dst = Y + (size_t)(m0 + row) * D_MODEL + n0 + o32;
    *(uint4*)dst = v0; *(uint4*)(dst + 8) = v1;
    *(uint4*)(dst + 16) = v2; *(uint4*)(dst + 24) = v3;
  }
}

// ---------------------------------------------------------------- attention
// One block per (b,h,qblock). 4 waves, each owns 32 query rows INDEPENDENTLY:
// Ps/rs are per-wave slices, so no block barriers — per-wave lgkmcnt ordering
// only (WSYNC). Waves drift freely -> cross-wave MFMA/VALU/VMEM overlap.
#define PSTR 264   // P lds row stride (elements)
#define OSTR 72    // O staging stride within Ps for coalesced store

template <int NF>   // number of 16-key fragments in window (16 normal, 8 last block)
__device__ __forceinline__ void attn_body(const u16* __restrict__ Qp,
                                          const u16* __restrict__ Kp,
                                          const u16* __restrict__ Vp,
                                          u16* __restrict__ X2p,
                                          u16* Ps, volatile float* rs) {
  const int lane = threadIdx.x & 63;
  const int fr = lane & 15, fg = lane >> 4;

  bf16x8 qf[2][2];
#pragma unroll
  for (int mf = 0; mf < 2; ++mf)
#pragma unroll
    for (int kk = 0; kk < 2; ++kk)
      qf[mf][kk] = *(const bf16x8*)(Qp + (mf * 16 + fr) * HEAD_DIM + kk * 32 + fg * 8);

  f32x4 sacc[2][NF];
#pragma unroll
  for (int mf = 0; mf < 2; ++mf)
#pragma unroll
    for (int nf = 0; nf < NF; ++nf) sacc[mf][nf] = (f32x4)(0.0f);

#pragma unroll
  for (int nf = 0; nf < NF; ++nf) {
    bf16x8 kf0 = *(const bf16x8*)(Kp + (nf * 16 + fr) * HEAD_DIM + fg * 8);
    bf16x8 kf1 = *(const bf16x8*)(Kp + (nf * 16 + fr) * HEAD_DIM + 32 + fg * 8);
#pragma unroll
    for (int mf = 0; mf < 2; ++mf) {
      sacc[mf][nf] = __builtin_amdgcn_mfma_f32_16x16x32_bf16(qf[mf][0], kf0, sacc[mf][nf], 0, 0, 0);
      sacc[mf][nf] = __builtin_amdgcn_mfma_f32_16x16x32_bf16(qf[mf][1], kf1, sacc[mf][nf], 0, 0, 0);
    }
  }

  // softmax: row m = mf*16 + fg*4 + r lives in lanes sharing fg, cols nf*16+fr
#pragma unroll
  for (int mf = 0; mf < 2; ++mf) {
#pragma unroll
    for (int r = 0; r < 4; ++r) {
      float mx = -1e30f;
#pragma unroll
      for (int nf = 0; nf < NF; ++nf) mx = fmaxf(mx, sacc[mf][nf][r]);
      mx = fmaxf(mx, __shfl_xor(mx, 1));
      mx = fmaxf(mx, __shfl_xor(mx, 2));
      mx = fmaxf(mx, __shfl_xor(mx, 4));
      mx = fmaxf(mx, __shfl_xor(mx, 8));
      float sm = 0.f;
#pragma unroll
      for (int nf = 0; nf < NF; ++nf) {
        float p = __expf(sacc[mf][nf][r] - mx);
        sacc[mf][nf][r] = p;
        sm += p;
      }
      sm += __shfl_xor(sm, 1);
      sm += __shfl_xor(sm, 2);
      sm += __shfl_xor(sm, 4);
      sm += __shfl_xor(sm, 8);
      if (fr == 0) rs[mf * 16 + fg * 4 + r] = sm;
    }
  }

  // P (exp, unnormalized) -> LDS bf16 (own-wave region)
#pragma unroll
  for (int mf = 0; mf < 2; ++mf)
#pragma unroll
    for (int nf = 0; nf < NF; ++nf)
#pragma unroll
      for (int r = 0; r < 4; ++r)
        Ps[(mf * 16 + fg * 4 + r) * PSTR + nf * 16 + fr] = f2b(sacc[mf][nf][r]);
  WSYNC();   // wave's P writes visible to its own reads

  // OUT^T[d][q] = sum_kk V^T[d][kk] * P^T[kk][q]
  f32x4 oacc[4][2];
#pragma unroll
  for (int mf2 = 0; mf2 < 4; ++mf2)
#pragma unroll
    for (int nf2 = 0; nf2 < 2; ++nf2) oacc[mf2][nf2] = (f32x4)(0.0f);

#pragma unroll
  for (int ks = 0; ks < NF / 2; ++ks) {
    bf16x8 vf[4];
#pragma unroll
    for (int mf2 = 0; mf2 < 4; ++mf2)
      vf[mf2] = *(const bf16x8*)(Vp + (size_t)(mf2 * 16 + fr) * SEQ + ks * 32 + fg * 8);
#pragma unroll
    for (int nf2 = 0; nf2 < 2; ++nf2) {
      bf16x8 pf = *(const bf16x8*)(Ps + (nf2 * 16 + fr) * PSTR + ks * 32 + fg * 8);
#pragma unroll
      for (int mf2 = 0; mf2 < 4; ++mf2)
        oacc[mf2][nf2] = __builtin_amdgcn_mfma_f32_16x16x32_bf16(vf[mf2], pf,
                                                                 oacc[mf2][nf2], 0, 0, 0);
    }
  }
  WSYNC();   // wave done reading P; reuse its Ps region for O staging

  // O -> LDS (normalized, [32 q][64 d] at stride OSTR), then 64B coalesced stores
#pragma unroll
  for (int nf2 = 0; nf2 < 2; ++nf2) {
    const int q = nf2 * 16 + fr;
    const float inv = 1.0f / rs[q];
#pragma unroll
    for (int mf2 = 0; mf2 < 4; ++mf2)
#pragma unroll
      for (int r = 0; r < 4; ++r)
        Ps[q * OSTR + mf2 * 16 + fg * 4 + r] = f2b(oacc[mf2][nf2][r] * inv);
  }
  WSYNC();
  const int q2 = lane >> 1, hf = (lane & 1) * 32;
  const u16* osrc = Ps + q2 * OSTR + hf;
  uint4 o0 = *(const uint4*)(osrc);
  uint4 o1 = *(const uint4*)(osrc + 8);
  uint4 o2 = *(const uint4*)(osrc + 16);
  uint4 o3 = *(const uint4*)(osrc + 24);
  u16* dst = X2p + (size_t)q2 * D_MODEL + hf;
  *(uint4*)dst = o0; *(uint4*)(dst + 8) = o1;
  *(uint4*)(dst + 16) = o2; *(uint4*)(dst + 24) = o3;
}

__global__ __launch_bounds__(256, 2) void attn_kernel(const u16* __restrict__ Qb,
                                                      const u16* __restrict__ Kb,
                                                      const u16* __restrict__ Vt,
                                                      u16* __restrict__ X2) {
  __shared__ u16 Ps[4][32 * PSTR];
  __shared__ float rs[4][32];
  const int bx = blockIdx.x;
  const int bh = bx >> 5, i = bx & 31;
  const int w = threadIdx.x >> 6;
  const int b = bh >> 4, h = bh & 15;
  const u16* Qp = Qb + ((size_t)bh * SEQ + i * 128 + w * 32) * HEAD_DIM;
  const u16* Kp = Kb + ((size_t)bh * SEQ + i * 128) * HEAD_DIM;
  const u16* Vp = Vt + (size_t)bh * HEAD_DIM * SEQ + i * 128;
  u16* X2p = X2 + ((size_t)(b * SEQ) + i * 128 + w * 32) * D_MODEL + h * HEAD_DIM;
  if (i == NBLK - 1) attn_body<8>(Qp, Kp, Vp, X2p, Ps[w], rs[w]);
  else               attn_body<16>(Qp, Kp, Vp, X2p, Ps[w], rs[w]);
}

// ---------------------------------------------------------------- layernorm
__global__ __launch_bounds__(256) void ln_kernel(const float* __restrict__ hidden,
                                                 const u16* __restrict__ Y,
                                                 const float* __restrict__ lw,
                                                 const float* __restrict__ lb,
                                                 float* __restrict__ out) {
  const int row = blockIdx.x;
  const int tid = threadIdx.x;
  const size_t base = (size_t)row * D_MODEL + tid * 4;
  float4 h = *(const float4*)(hidden + base);
  union { uint2 v; u16 u[4]; } y;
  y.v = *(const uint2*)(Y + base);
  float x0 = h.x + b2f(y.u[0]);
  float x1 = h.y + b2f(y.u[1]);
  float x2 = h.z + b2f(y.u[2]);
  float x3 = h.w + b2f(y.u[3]);
  float sum = x0 + x1 + x2 + x3;
  float sq  = x0 * x0 + x1 * x1 + x2 * x2 + x3 * x3;
#pragma unroll
  for (int off = 32; off >= 1; off >>= 1) {
    sum += __shfl_down(sum, off);
    sq  += __shfl_down(sq, off);
  }
  __shared__ float s1[4], s2[4];
  const int w = tid >> 6, lane = tid & 63;
  if (lane == 0) { s1[w] = sum; s2[w] = sq; }
  __syncthreads();
  const float ts = s1[0] + s1[1] + s1[2] + s1[3];
  const float tq = s2[0] + s2[1] + s2[2] + s2[3];
  const float mu = ts * (1.0f / 1024.0f);
  const float var = tq * (1.0f / 1024.0f) - mu * mu;
  const float rstd = rsqrtf(var + 1e-5f);
  float4 lwv = *(const float4*)(lw + tid * 4);
  float4 lbv = *(const float4*)(lb + tid * 4);
  float4 o;
  o.x = (x0 - mu) * rstd * lwv.x + lbv.x;
  o.y = (x1 - mu) * rstd * lwv.y + lbv.y;
  o.z = (x2 - mu) * rstd * lwv.z + lbv.z;
  o.w = (x3 - mu) * rstd * lwv.w + lbv.w;
  *(float4*)(out + base) = o;
}

// ---------------------------------------------------------------- launcher
extern "C" void kernel_launch(void* const* d_in, const int* in_sizes, int n_in,
                              void* d_out, int out_size, void* d_ws, size_t ws_size,
                              hipStream_t stream) {
  const float* hidden = (const float*)d_in[0];
  const float* Wq = (const float*)d_in[1];
  const float* bq = (const float*)d_in[2];
  const float* Wk = (const float*)d_in[3];
  const float* bk = (const float*)d_in[4];
  const float* Wv = (const float*)d_in[5];
  const float* bv = (const float*)d_in[6];
  const float* Wo = (const float*)d_in[7];
  const float* bo = (const float*)d_in[8];
  const float* lw = (const float*)d_in[9];
  const float* lb = (const float*)d_in[10];
  float* out = (float*)d_out;

  u16* Xb = (u16*)d_ws;                                  // [8192][1024]
  u16* Wt = Xb + (size_t)MROWS * D_MODEL;                // [4][1024 n][1024 k]
  u16* Qb = Wt + (size_t)4 * D_MODEL * D_MODEL;          // [32][4096][64] (q*0.125)
  u16* Kb = Qb + (size_t)32 * SEQ * HEAD_DIM;            // [32][4096][64]
  u16* Vt = Kb + (size_t)32 * SEQ * HEAD_DIM;            // [32][64][4096]
  u16* X2 = Vt + (size_t)32 * SEQ * HEAD_DIM;            // [8192][1024] attn out
  u16* Y  = X2 + (size_t)MROWS * D_MODEL;                // [8192][1024] o-proj out

  convert_x_kernel<<<4096, 256, 0, stream>>>(hidden, Xb);
  transpose_w_kernel<<<dim3(32, 32, 4), 256, 0, stream>>>(Wq, Wk, Wv, Wo, Wt);
  qkv_gemm_kernel<<<1536, 256, 0, stream>>>(Xb, Wt, bq, bk, bv, Qb, Kb, Vt);
  attn_kernel<<<1024, 256, 0, stream>>>(Qb, Kb, Vt, X2);
  o_gemm_kernel<<<512, 256, 0, stream>>>(X2, Wt + (size_t)3 * D_MODEL * D_MODEL, bo, Y);
  ln_kernel<<<MROWS, 256, 0, stream>>>(hidden, Y, lw, lb, out);
}